// Round 13
// baseline (1042.924 us; speedup 1.0000x reference)
//
#include <hip/hip_runtime.h>
#include <hip/hip_bf16.h>
#include <hip/hip_fp16.h>

typedef _Float16 h2vec __attribute__((ext_vector_type(2)));
typedef _Float16 f16x8 __attribute__((ext_vector_type(8)));
typedef float f32x4 __attribute__((ext_vector_type(4)));

static __device__ __forceinline__ float fast_sigmoid(float x) {
  return __builtin_amdgcn_rcpf(1.f + __expf(-x));
}
static __device__ __forceinline__ float fast_tanh(float x) {
  return 1.f - 2.f * __builtin_amdgcn_rcpf(__expf(2.f * x) + 1.f);
}
static __device__ __forceinline__ float fdot2u(unsigned int a, unsigned int b, float c) {
#if __has_builtin(__builtin_amdgcn_fdot2)
  return __builtin_amdgcn_fdot2(__builtin_bit_cast(h2vec, a),
                                __builtin_bit_cast(h2vec, b), c, false);
#else
  h2vec av = __builtin_bit_cast(h2vec, a);
  h2vec bv = __builtin_bit_cast(h2vec, b);
  return c + (float)av[0] * (float)bv[0] + (float)av[1] * (float)bv[1];
#endif
}
template<int CTRL>
static __device__ __forceinline__ float dpp_add(float v) {
  int x = __builtin_bit_cast(int, v);
  int y = __builtin_amdgcn_update_dpp(0, x, CTRL, 0xF, 0xF, true);
  return v + __builtin_bit_cast(float, y);
}
template<int CTRL>
static __device__ __forceinline__ float dpp_mov(float v) {
  int x = __builtin_bit_cast(int, v);
  int y = __builtin_amdgcn_update_dpp(0, x, CTRL, 0xF, 0xF, true);
  return __builtin_bit_cast(float, y);
}

// ---------------------------------------------------------------------------
// A-tile staging helper: f32 or f16 source -> f16 swizzled LDS rows (128B).
// ---------------------------------------------------------------------------
template<typename AT>
static __device__ __forceinline__ void stage_row32(
    const AT* __restrict__ src, unsigned char* __restrict__ dst,
    int row, int kc) {
#pragma unroll
  for (int u = 0; u < 4; ++u) {
    f16x8 h;
    if constexpr (sizeof(AT) == 4) {
      float4 v0 = *reinterpret_cast<const float4*>((const float*)src + u * 8);
      float4 v1 = *reinterpret_cast<const float4*>((const float*)src + u * 8 + 4);
      h[0] = (_Float16)v0.x; h[1] = (_Float16)v0.y;
      h[2] = (_Float16)v0.z; h[3] = (_Float16)v0.w;
      h[4] = (_Float16)v1.x; h[5] = (_Float16)v1.y;
      h[6] = (_Float16)v1.z; h[7] = (_Float16)v1.w;
    } else {
      h = *reinterpret_cast<const f16x8*>((const __half*)src + u * 8);
    }
    const int kbyte = (kc + u * 8) * 2;
    *reinterpret_cast<f16x8*>(&dst[row * 128 + (kbyte ^ ((row & 7) << 4))]) = h;
  }
}

// ---------------------------------------------------------------------------
// f16-MFMA GEMM. C = act(A @ W^T + bias). Proven 128x64x64 swizzled tile.
// MODE 0: +b0+b1; MODE 1: relu(+b0); MODE 2: tanh(+b0).
// ---------------------------------------------------------------------------
template<typename AT, typename OT, int MODE>
__global__ __launch_bounds__(256) void gemm_mfma2(
    const AT* __restrict__ A, const float* __restrict__ W,
    const float* __restrict__ b0, const float* __restrict__ b1,
    OT* __restrict__ C, int M, int N, int K) {
  __shared__ __align__(16) unsigned char As[128 * 128];
  __shared__ __align__(16) unsigned char Bs[64 * 128];
  const int tid = threadIdx.x;
  const int wave = tid >> 6, l = tid & 63;
  const int wm = wave >> 1, wn = wave & 1;
  const int m0 = blockIdx.x * 128, n0 = blockIdx.y * 64;
  const int lrow = l & 15, lq = l >> 4;

  f32x4 acc[4][2] = {};
  const int arow = tid >> 1, akc = (tid & 1) * 32;
  const int brow = tid >> 2, bkc = (tid & 3) * 16;

  for (int k0 = 0; k0 < K; k0 += 64) {
    stage_row32<AT>(A + (size_t)(m0 + arow) * K + k0 + akc, As, arow, akc);
    {
      const float* src = W + (size_t)(n0 + brow) * K + k0 + bkc;
#pragma unroll
      for (int u = 0; u < 2; ++u) {
        float4 v0 = *reinterpret_cast<const float4*>(src + u * 8);
        float4 v1 = *reinterpret_cast<const float4*>(src + u * 8 + 4);
        f16x8 h;
        h[0] = (_Float16)v0.x; h[1] = (_Float16)v0.y;
        h[2] = (_Float16)v0.z; h[3] = (_Float16)v0.w;
        h[4] = (_Float16)v1.x; h[5] = (_Float16)v1.y;
        h[6] = (_Float16)v1.z; h[7] = (_Float16)v1.w;
        const int kbyte = (bkc + u * 8) * 2;
        *reinterpret_cast<f16x8*>(&Bs[brow * 128 + (kbyte ^ ((brow & 7) << 4))]) = h;
      }
    }
    __syncthreads();
#pragma unroll
    for (int kk = 0; kk < 64; kk += 32) {
      const int kbyte = (kk + lq * 8) * 2;
      f16x8 af[4], bf[2];
#pragma unroll
      for (int mt = 0; mt < 4; ++mt) {
        const int row = wm * 64 + mt * 16 + lrow;
        af[mt] = *reinterpret_cast<const f16x8*>(&As[row * 128 + (kbyte ^ ((row & 7) << 4))]);
      }
#pragma unroll
      for (int nt = 0; nt < 2; ++nt) {
        const int row = wn * 32 + nt * 16 + lrow;
        bf[nt] = *reinterpret_cast<const f16x8*>(&Bs[row * 128 + (kbyte ^ ((row & 7) << 4))]);
      }
#pragma unroll
      for (int mt = 0; mt < 4; ++mt)
#pragma unroll
        for (int nt = 0; nt < 2; ++nt)
          acc[mt][nt] = __builtin_amdgcn_mfma_f32_16x16x32_f16(af[mt], bf[nt], acc[mt][nt], 0, 0, 0);
    }
    __syncthreads();
  }

#pragma unroll
  for (int nt = 0; nt < 2; ++nt) {
    const int n = n0 + wn * 32 + nt * 16 + lrow;
    float bias = (MODE == 0) ? (b0[n] + b1[n]) : b0[n];
#pragma unroll
    for (int mt = 0; mt < 4; ++mt) {
#pragma unroll
      for (int r = 0; r < 4; ++r) {
        const int m = m0 + wm * 64 + mt * 16 + lq * 4 + r;
        float val = acc[mt][nt][r] + bias;
        if (MODE == 1) val = fmaxf(val, 0.f);
        if (MODE == 2) val = fast_tanh(val);
        if constexpr (sizeof(OT) == 2)
          C[(size_t)m * N + n] = __float2half_rn(val);
        else
          C[(size_t)m * N + n] = val;
      }
    }
  }
}

// ---------------------------------------------------------------------------
// Fused fw+bw input-projection GEMM, f16 output. blockIdx.z = direction.
// ---------------------------------------------------------------------------
template<typename AT>
__global__ __launch_bounds__(256) void gemm_proj_h(
    const AT* __restrict__ A,
    const float* __restrict__ W0, const float* __restrict__ W1,
    const float* __restrict__ bi0, const float* __restrict__ bh0,
    const float* __restrict__ bi1, const float* __restrict__ bh1,
    __half* __restrict__ C0, __half* __restrict__ C1, int M, int N, int K) {
  const float* __restrict__ W  = blockIdx.z ? W1 : W0;
  const float* __restrict__ b0 = blockIdx.z ? bi1 : bi0;
  const float* __restrict__ b1 = blockIdx.z ? bh1 : bh0;
  __half* __restrict__ C = blockIdx.z ? C1 : C0;

  __shared__ __align__(16) unsigned char As[128 * 128];
  __shared__ __align__(16) unsigned char Bs[64 * 128];
  const int tid = threadIdx.x;
  const int wave = tid >> 6, l = tid & 63;
  const int wm = wave >> 1, wn = wave & 1;
  const int m0 = blockIdx.x * 128, n0 = blockIdx.y * 64;
  const int lrow = l & 15, lq = l >> 4;

  f32x4 acc[4][2] = {};
  const int arow = tid >> 1, akc = (tid & 1) * 32;
  const int brow = tid >> 2, bkc = (tid & 3) * 16;

  for (int k0 = 0; k0 < K; k0 += 64) {
    stage_row32<AT>(A + (size_t)(m0 + arow) * K + k0 + akc, As, arow, akc);
    {
      const float* src = W + (size_t)(n0 + brow) * K + k0 + bkc;
#pragma unroll
      for (int u = 0; u < 2; ++u) {
        float4 v0 = *reinterpret_cast<const float4*>(src + u * 8);
        float4 v1 = *reinterpret_cast<const float4*>(src + u * 8 + 4);
        f16x8 h;
        h[0] = (_Float16)v0.x; h[1] = (_Float16)v0.y;
        h[2] = (_Float16)v0.z; h[3] = (_Float16)v0.w;
        h[4] = (_Float16)v1.x; h[5] = (_Float16)v1.y;
        h[6] = (_Float16)v1.z; h[7] = (_Float16)v1.w;
        const int kbyte = (bkc + u * 8) * 2;
        *reinterpret_cast<f16x8*>(&Bs[brow * 128 + (kbyte ^ ((brow & 7) << 4))]) = h;
      }
    }
    __syncthreads();
#pragma unroll
    for (int kk = 0; kk < 64; kk += 32) {
      const int kbyte = (kk + lq * 8) * 2;
      f16x8 af[4], bf[2];
#pragma unroll
      for (int mt = 0; mt < 4; ++mt) {
        const int row = wm * 64 + mt * 16 + lrow;
        af[mt] = *reinterpret_cast<const f16x8*>(&As[row * 128 + (kbyte ^ ((row & 7) << 4))]);
      }
#pragma unroll
      for (int nt = 0; nt < 2; ++nt) {
        const int row = wn * 32 + nt * 16 + lrow;
        bf[nt] = *reinterpret_cast<const f16x8*>(&Bs[row * 128 + (kbyte ^ ((row & 7) << 4))]);
      }
#pragma unroll
      for (int mt = 0; mt < 4; ++mt)
#pragma unroll
        for (int nt = 0; nt < 2; ++nt)
          acc[mt][nt] = __builtin_amdgcn_mfma_f32_16x16x32_f16(af[mt], bf[nt], acc[mt][nt], 0, 0, 0);
    }
    __syncthreads();
  }

#pragma unroll
  for (int nt = 0; nt < 2; ++nt) {
    const int n = n0 + wn * 32 + nt * 16 + lrow;
    const float bias = b0[n] + b1[n];
#pragma unroll
    for (int mt = 0; mt < 4; ++mt) {
#pragma unroll
      for (int r = 0; r < 4; ++r) {
        const int m = m0 + wm * 64 + mt * 16 + lq * 4 + r;
        C[(size_t)m * N + n] = __float2half_rn(acc[mt][nt][r] + bias);
      }
    }
  }
}

// ---------------------------------------------------------------------------
// LSTM recurrence, v10 "dual": one 512-thread block per BATCH; each lane
// runs BOTH directions (A = fw, B = bw) with instruction-interleaved
// independent chains -> in-lane ILP breaks the correlated-stall lockstep
// that wave-pairing (v3) could not. Lane (j = tid>>2 unit, kq = tid&3
// k-quarter): per dir, 4 gate-rows over k-quarter = 64 dot2; 128 total.
// Per-dir quad DPP allreduce + single-gate activation (tanh = 2*sig(2x)-1)
// + quad broadcasts. h per dir in separate LDS buffers (double-buffered).
// One raw lgkmcnt-only barrier per step serves both dirs. f16 xg,
// prefetch depth 2. v9 despill style (named scalars, macro dots).
// ---------------------------------------------------------------------------
__global__ __launch_bounds__(512, 2) void lstm_dual(
    const __half* __restrict__ xg_f, const __half* __restrict__ xg_b,
    const float* __restrict__ Whh_f, const float* __restrict__ Whh_b,
    __half* __restrict__ out) {
  const int b = blockIdx.x;
  const int tid = threadIdx.x;
  const int j = tid >> 2;   // unit 0..127
  const int kq = tid & 3;   // k quarter

  __shared__ unsigned int hbuf[2][2][64];  // [dir][buf][dword] f16 pairs

  // Weights both dirs: w*[g][kk] = f16x2 of row (g*128+j), k = kq*32+2*kk
  unsigned int wa[4][16], wb[4][16];
#pragma unroll
  for (int g = 0; g < 4; ++g) {
    const float4* wrA = reinterpret_cast<const float4*>(
        Whh_f + (size_t)(g * 128 + j) * 128 + kq * 32);
    const float4* wrB = reinterpret_cast<const float4*>(
        Whh_b + (size_t)(g * 128 + j) * 128 + kq * 32);
#pragma unroll
    for (int q = 0; q < 8; ++q) {
      float4 va = wrA[q];
      float4 vb = wrB[q];
      wa[g][2 * q]     = __builtin_bit_cast(unsigned int, __floats2half2_rn(va.x, va.y));
      wa[g][2 * q + 1] = __builtin_bit_cast(unsigned int, __floats2half2_rn(va.z, va.w));
      wb[g][2 * q]     = __builtin_bit_cast(unsigned int, __floats2half2_rn(vb.x, vb.y));
      wb[g][2 * q + 1] = __builtin_bit_cast(unsigned int, __floats2half2_rn(vb.z, vb.w));
    }
  }

  if (tid < 256) reinterpret_cast<unsigned int*>(hbuf)[tid] = 0u;
  float ca = 0.f, cb = 0.f;
  __syncthreads();

  const size_t base = (size_t)b * 512 * 512;
  const int xidx = kq * 128 + j;

  // depth-2 xg prefetch, both dirs (A: t = 0,1..., B: t = 511,510...)
  unsigned short xaA = __builtin_bit_cast(unsigned short, xg_f[base + (size_t)0 * 512 + xidx]);
  unsigned short xbA = __builtin_bit_cast(unsigned short, xg_f[base + (size_t)1 * 512 + xidx]);
  unsigned short xaB = __builtin_bit_cast(unsigned short, xg_b[base + (size_t)511 * 512 + xidx]);
  unsigned short xbB = __builtin_bit_cast(unsigned short, xg_b[base + (size_t)510 * 512 + xidx]);

  auto step = [&](int t, unsigned int* rA, unsigned int* wA_,
                  unsigned int* rB, unsigned int* wB_,
                  unsigned short& xcA, unsigned short& xcB)
      __attribute__((always_inline)) {
    const int ttA = t;
    const int ttB = 511 - t;

    // h quarters, both dirs: 8 x ds_read_b128 issued back-to-back
    const uint4* hcA = reinterpret_cast<const uint4*>(&rA[kq * 16]);
    const uint4* hcB = reinterpret_cast<const uint4*>(&rB[kq * 16]);
    const uint4 qA0 = hcA[0], qA1 = hcA[1], qA2 = hcA[2], qA3 = hcA[3];
    const uint4 qB0 = hcB[0], qB1 = hcB[1], qB2 = hcB[2], qB3 = hcB[3];

    float aA0 = 0.f, aA1 = 0.f, aA2 = 0.f, aA3 = 0.f;
    float aB0 = 0.f, aB1 = 0.f, aB2 = 0.f, aB3 = 0.f;
#define ACC2(kk, hA, hB)                     \
    aA0 = fdot2u(wa[0][kk], (hA), aA0);      \
    aB0 = fdot2u(wb[0][kk], (hB), aB0);      \
    aA1 = fdot2u(wa[1][kk], (hA), aA1);      \
    aB1 = fdot2u(wb[1][kk], (hB), aB1);      \
    aA2 = fdot2u(wa[2][kk], (hA), aA2);      \
    aB2 = fdot2u(wb[2][kk], (hB), aB2);      \
    aA3 = fdot2u(wa[3][kk], (hA), aA3);      \
    aB3 = fdot2u(wb[3][kk], (hB), aB3);
    ACC2(0,  qA0.x, qB0.x) ACC2(1,  qA0.y, qB0.y)
    ACC2(2,  qA0.z, qB0.z) ACC2(3,  qA0.w, qB0.w)
    ACC2(4,  qA1.x, qB1.x) ACC2(5,  qA1.y, qB1.y)
    ACC2(6,  qA1.z, qB1.z) ACC2(7,  qA1.w, qB1.w)
    ACC2(8,  qA2.x, qB2.x) ACC2(9,  qA2.y, qB2.y)
    ACC2(10, qA2.z, qB2.z) ACC2(11, qA2.w, qB2.w)
    ACC2(12, qA3.x, qB3.x) ACC2(13, qA3.y, qB3.y)
    ACC2(14, qA3.z, qB3.z) ACC2(15, qA3.w, qB3.w)
#undef ACC2

    // quad butterflies, interleaved
    aA0 = dpp_add<0x4E>(dpp_add<0xB1>(aA0));
    aB0 = dpp_add<0x4E>(dpp_add<0xB1>(aB0));
    aA1 = dpp_add<0x4E>(dpp_add<0xB1>(aA1));
    aB1 = dpp_add<0x4E>(dpp_add<0xB1>(aB1));
    aA2 = dpp_add<0x4E>(dpp_add<0xB1>(aA2));
    aB2 = dpp_add<0x4E>(dpp_add<0xB1>(aB2));
    aA3 = dpp_add<0x4E>(dpp_add<0xB1>(aA3));
    aB3 = dpp_add<0x4E>(dpp_add<0xB1>(aB3));

    // gate select + xg add
    float sA = aA0;
    sA = (kq == 1) ? aA1 : sA;
    sA = (kq == 2) ? aA2 : sA;
    sA = (kq == 3) ? aA3 : sA;
    sA += (float)__builtin_bit_cast(_Float16, xcA);
    float sB = aB0;
    sB = (kq == 1) ? aB1 : sB;
    sB = (kq == 2) ? aB2 : sB;
    sB = (kq == 3) ? aB3 : sB;
    sB += (float)__builtin_bit_cast(_Float16, xcB);

    // prefetch xg for t+2, both dirs (in flight across raw barriers)
    {
      const int t2 = t + 2;
      const int tA2 = (t2 < 512) ? t2 : 0;
      const int tB2 = (t2 < 512) ? (511 - t2) : 511;
      xcA = __builtin_bit_cast(unsigned short, xg_f[base + (size_t)tA2 * 512 + xidx]);
      xcB = __builtin_bit_cast(unsigned short, xg_b[base + (size_t)tB2 * 512 + xidx]);
    }

    // activations, interleaved independent chains
    const float xsA = (kq == 2) ? 2.f * sA : sA;
    const float xsB = (kq == 2) ? 2.f * sB : sB;
    const float yA = fast_sigmoid(xsA);
    const float yB = fast_sigmoid(xsB);
    const float actA = (kq == 2) ? 2.f * yA - 1.f : yA;
    const float actB = (kq == 2) ? 2.f * yB - 1.f : yB;

    const float giA = dpp_mov<0x00>(actA);
    const float giB = dpp_mov<0x00>(actB);
    const float gfA = dpp_mov<0x55>(actA);
    const float gfB = dpp_mov<0x55>(actB);
    const float ggA = dpp_mov<0xAA>(actA);
    const float ggB = dpp_mov<0xAA>(actB);
    const float goA = dpp_mov<0xFF>(actA);
    const float goB = dpp_mov<0xFF>(actB);

    ca = gfA * ca + giA * ggA;
    cb = gfB * cb + giB * ggB;
    const float hA = goA * (2.f * fast_sigmoid(2.f * ca) - 1.f);
    const float hB = goB * (2.f * fast_sigmoid(2.f * cb) - 1.f);

    if (kq == 0) {  // h -> next step's buffers (f16)
      reinterpret_cast<unsigned short*>(wA_)[j] =
          __builtin_bit_cast(unsigned short, (_Float16)hA);
      reinterpret_cast<unsigned short*>(wB_)[j] =
          __builtin_bit_cast(unsigned short, (_Float16)hB);
    }
    if (kq == 1) {  // h -> global out (f16), dir offsets 0 / 128
      out[((size_t)b * 512 + ttA) * 256 + j] = __float2half_rn(hA);
      out[((size_t)b * 512 + ttB) * 256 + 128 + j] = __float2half_rn(hB);
    }

    asm volatile("s_waitcnt lgkmcnt(0)" ::: "memory");
    __builtin_amdgcn_s_barrier();
    asm volatile("" ::: "memory");
  };

  for (int it = 0; it < 256; ++it) {
    step(2 * it,     hbuf[0][0], hbuf[0][1], hbuf[1][0], hbuf[1][1], xaA, xaB);
    step(2 * it + 1, hbuf[0][1], hbuf[0][0], hbuf[1][1], hbuf[1][0], xbA, xbB);
  }
}

// ---------------------------------------------------------------------------
// Launcher
// ---------------------------------------------------------------------------
extern "C" void kernel_launch(void* const* d_in, const int* in_sizes, int n_in,
                              void* d_out, int out_size, void* d_ws, size_t ws_size,
                              hipStream_t stream) {
  (void)in_sizes; (void)n_in; (void)out_size; (void)ws_size;

  const float* x     = (const float*)d_in[0];
  const float* Wih00 = (const float*)d_in[1];
  const float* Whh00 = (const float*)d_in[2];
  const float* bih00 = (const float*)d_in[3];
  const float* bhh00 = (const float*)d_in[4];
  const float* Wih01 = (const float*)d_in[5];
  const float* Whh01 = (const float*)d_in[6];
  const float* bih01 = (const float*)d_in[7];
  const float* bhh01 = (const float*)d_in[8];
  const float* Wih10 = (const float*)d_in[9];
  const float* Whh10 = (const float*)d_in[10];
  const float* bih10 = (const float*)d_in[11];
  const float* bhh10 = (const float*)d_in[12];
  const float* Wih11 = (const float*)d_in[13];
  const float* Whh11 = (const float*)d_in[14];
  const float* bih11 = (const float*)d_in[15];
  const float* bhh11 = (const float*)d_in[16];
  const float* W1 = (const float*)d_in[17];
  const float* b1 = (const float*)d_in[18];
  const float* W2 = (const float*)d_in[19];
  const float* b2 = (const float*)d_in[20];
  float* out = (float*)d_out;

  char* ws = (char*)d_ws;
  __half* xgh_f = (__half*)ws;                          // 32 MB [B,T,512] f16
  __half* xgh_b = (__half*)(ws + ((size_t)32 << 20));   // 32 MB
  __half* bufh  = (__half*)(ws + ((size_t)64 << 20));   // 16 MB [B,T,256] f16
  __half* tmph  = (__half*)(ws + ((size_t)80 << 20));   // 16 MB head intermediate

  const int M = 64 * 512;  // 32768 rows

  // ---- layer 0 ----
  gemm_proj_h<float><<<dim3(M / 128, 8, 2), 256, 0, stream>>>(
      x, Wih00, Wih01, bih00, bhh00, bih01, bhh01, xgh_f, xgh_b, M, 512, 64);
  lstm_dual<<<dim3(64), 512, 0, stream>>>(xgh_f, xgh_b, Whh00, Whh01, bufh);

  // ---- layer 1 ----
  gemm_proj_h<__half><<<dim3(M / 128, 8, 2), 256, 0, stream>>>(
      bufh, Wih10, Wih11, bih10, bhh10, bih11, bhh11, xgh_f, xgh_b, M, 512, 256);
  lstm_dual<<<dim3(64), 512, 0, stream>>>(xgh_f, xgh_b, Whh10, Whh11, bufh);

  // ---- head ----
  gemm_mfma2<__half, __half, 1><<<dim3(M / 128, 4), 256, 0, stream>>>(
      bufh, W1, b1, nullptr, tmph, M, 256, 256);
  gemm_mfma2<__half, float, 2><<<dim3(M / 128, 1), 256, 0, stream>>>(
      tmph, W2, b2, nullptr, out, M, 64, 256);
}

// Round 14
// 630.261 us; speedup vs baseline: 1.6548x; 1.6548x over previous
//
#include <hip/hip_runtime.h>
#include <hip/hip_bf16.h>
#include <hip/hip_fp16.h>

typedef _Float16 h2vec __attribute__((ext_vector_type(2)));
typedef _Float16 f16x8 __attribute__((ext_vector_type(8)));
typedef float f32x4 __attribute__((ext_vector_type(4)));

static __device__ __forceinline__ float fast_sigmoid(float x) {
  return __builtin_amdgcn_rcpf(1.f + __expf(-x));
}
static __device__ __forceinline__ float fast_tanh(float x) {
  return 1.f - 2.f * __builtin_amdgcn_rcpf(__expf(2.f * x) + 1.f);
}
static __device__ __forceinline__ float fdot2u(unsigned int a, unsigned int b, float c) {
#if __has_builtin(__builtin_amdgcn_fdot2)
  return __builtin_amdgcn_fdot2(__builtin_bit_cast(h2vec, a),
                                __builtin_bit_cast(h2vec, b), c, false);
#else
  h2vec av = __builtin_bit_cast(h2vec, a);
  h2vec bv = __builtin_bit_cast(h2vec, b);
  return c + (float)av[0] * (float)bv[0] + (float)av[1] * (float)bv[1];
#endif
}
template<int CTRL>
static __device__ __forceinline__ float dpp_add(float v) {
  int x = __builtin_bit_cast(int, v);
  int y = __builtin_amdgcn_update_dpp(0, x, CTRL, 0xF, 0xF, true);
  return v + __builtin_bit_cast(float, y);
}
template<int CTRL>
static __device__ __forceinline__ float dpp_mov(float v) {
  int x = __builtin_bit_cast(int, v);
  int y = __builtin_amdgcn_update_dpp(0, x, CTRL, 0xF, 0xF, true);
  return __builtin_bit_cast(float, y);
}

// ---------------------------------------------------------------------------
// A-tile staging helper: f32 or f16 source -> f16 swizzled LDS rows (128B).
// ---------------------------------------------------------------------------
template<typename AT>
static __device__ __forceinline__ void stage_row32(
    const AT* __restrict__ src, unsigned char* __restrict__ dst,
    int row, int kc) {
#pragma unroll
  for (int u = 0; u < 4; ++u) {
    f16x8 h;
    if constexpr (sizeof(AT) == 4) {
      float4 v0 = *reinterpret_cast<const float4*>((const float*)src + u * 8);
      float4 v1 = *reinterpret_cast<const float4*>((const float*)src + u * 8 + 4);
      h[0] = (_Float16)v0.x; h[1] = (_Float16)v0.y;
      h[2] = (_Float16)v0.z; h[3] = (_Float16)v0.w;
      h[4] = (_Float16)v1.x; h[5] = (_Float16)v1.y;
      h[6] = (_Float16)v1.z; h[7] = (_Float16)v1.w;
    } else {
      h = *reinterpret_cast<const f16x8*>((const __half*)src + u * 8);
    }
    const int kbyte = (kc + u * 8) * 2;
    *reinterpret_cast<f16x8*>(&dst[row * 128 + (kbyte ^ ((row & 7) << 4))]) = h;
  }
}

// ---------------------------------------------------------------------------
// f16-MFMA GEMM. C = act(A @ W^T + bias). Proven 128x64x64 swizzled tile.
// MODE 0: +b0+b1; MODE 1: relu(+b0); MODE 2: tanh(+b0).
// ---------------------------------------------------------------------------
template<typename AT, typename OT, int MODE>
__global__ __launch_bounds__(256) void gemm_mfma2(
    const AT* __restrict__ A, const float* __restrict__ W,
    const float* __restrict__ b0, const float* __restrict__ b1,
    OT* __restrict__ C, int M, int N, int K) {
  __shared__ __align__(16) unsigned char As[128 * 128];
  __shared__ __align__(16) unsigned char Bs[64 * 128];
  const int tid = threadIdx.x;
  const int wave = tid >> 6, l = tid & 63;
  const int wm = wave >> 1, wn = wave & 1;
  const int m0 = blockIdx.x * 128, n0 = blockIdx.y * 64;
  const int lrow = l & 15, lq = l >> 4;

  f32x4 acc[4][2] = {};
  const int arow = tid >> 1, akc = (tid & 1) * 32;
  const int brow = tid >> 2, bkc = (tid & 3) * 16;

  for (int k0 = 0; k0 < K; k0 += 64) {
    stage_row32<AT>(A + (size_t)(m0 + arow) * K + k0 + akc, As, arow, akc);
    {
      const float* src = W + (size_t)(n0 + brow) * K + k0 + bkc;
#pragma unroll
      for (int u = 0; u < 2; ++u) {
        float4 v0 = *reinterpret_cast<const float4*>(src + u * 8);
        float4 v1 = *reinterpret_cast<const float4*>(src + u * 8 + 4);
        f16x8 h;
        h[0] = (_Float16)v0.x; h[1] = (_Float16)v0.y;
        h[2] = (_Float16)v0.z; h[3] = (_Float16)v0.w;
        h[4] = (_Float16)v1.x; h[5] = (_Float16)v1.y;
        h[6] = (_Float16)v1.z; h[7] = (_Float16)v1.w;
        const int kbyte = (bkc + u * 8) * 2;
        *reinterpret_cast<f16x8*>(&Bs[brow * 128 + (kbyte ^ ((brow & 7) << 4))]) = h;
      }
    }
    __syncthreads();
#pragma unroll
    for (int kk = 0; kk < 64; kk += 32) {
      const int kbyte = (kk + lq * 8) * 2;
      f16x8 af[4], bf[2];
#pragma unroll
      for (int mt = 0; mt < 4; ++mt) {
        const int row = wm * 64 + mt * 16 + lrow;
        af[mt] = *reinterpret_cast<const f16x8*>(&As[row * 128 + (kbyte ^ ((row & 7) << 4))]);
      }
#pragma unroll
      for (int nt = 0; nt < 2; ++nt) {
        const int row = wn * 32 + nt * 16 + lrow;
        bf[nt] = *reinterpret_cast<const f16x8*>(&Bs[row * 128 + (kbyte ^ ((row & 7) << 4))]);
      }
#pragma unroll
      for (int mt = 0; mt < 4; ++mt)
#pragma unroll
        for (int nt = 0; nt < 2; ++nt)
          acc[mt][nt] = __builtin_amdgcn_mfma_f32_16x16x32_f16(af[mt], bf[nt], acc[mt][nt], 0, 0, 0);
    }
    __syncthreads();
  }

#pragma unroll
  for (int nt = 0; nt < 2; ++nt) {
    const int n = n0 + wn * 32 + nt * 16 + lrow;
    float bias = (MODE == 0) ? (b0[n] + b1[n]) : b0[n];
#pragma unroll
    for (int mt = 0; mt < 4; ++mt) {
#pragma unroll
      for (int r = 0; r < 4; ++r) {
        const int m = m0 + wm * 64 + mt * 16 + lq * 4 + r;
        float val = acc[mt][nt][r] + bias;
        if (MODE == 1) val = fmaxf(val, 0.f);
        if (MODE == 2) val = fast_tanh(val);
        if constexpr (sizeof(OT) == 2)
          C[(size_t)m * N + n] = __float2half_rn(val);
        else
          C[(size_t)m * N + n] = val;
      }
    }
  }
}

// ---------------------------------------------------------------------------
// Fused fw+bw input-projection GEMM, f16 output. blockIdx.z = direction.
// ---------------------------------------------------------------------------
template<typename AT>
__global__ __launch_bounds__(256) void gemm_proj_h(
    const AT* __restrict__ A,
    const float* __restrict__ W0, const float* __restrict__ W1,
    const float* __restrict__ bi0, const float* __restrict__ bh0,
    const float* __restrict__ bi1, const float* __restrict__ bh1,
    __half* __restrict__ C0, __half* __restrict__ C1, int M, int N, int K) {
  const float* __restrict__ W  = blockIdx.z ? W1 : W0;
  const float* __restrict__ b0 = blockIdx.z ? bi1 : bi0;
  const float* __restrict__ b1 = blockIdx.z ? bh1 : bh0;
  __half* __restrict__ C = blockIdx.z ? C1 : C0;

  __shared__ __align__(16) unsigned char As[128 * 128];
  __shared__ __align__(16) unsigned char Bs[64 * 128];
  const int tid = threadIdx.x;
  const int wave = tid >> 6, l = tid & 63;
  const int wm = wave >> 1, wn = wave & 1;
  const int m0 = blockIdx.x * 128, n0 = blockIdx.y * 64;
  const int lrow = l & 15, lq = l >> 4;

  f32x4 acc[4][2] = {};
  const int arow = tid >> 1, akc = (tid & 1) * 32;
  const int brow = tid >> 2, bkc = (tid & 3) * 16;

  for (int k0 = 0; k0 < K; k0 += 64) {
    stage_row32<AT>(A + (size_t)(m0 + arow) * K + k0 + akc, As, arow, akc);
    {
      const float* src = W + (size_t)(n0 + brow) * K + k0 + bkc;
#pragma unroll
      for (int u = 0; u < 2; ++u) {
        float4 v0 = *reinterpret_cast<const float4*>(src + u * 8);
        float4 v1 = *reinterpret_cast<const float4*>(src + u * 8 + 4);
        f16x8 h;
        h[0] = (_Float16)v0.x; h[1] = (_Float16)v0.y;
        h[2] = (_Float16)v0.z; h[3] = (_Float16)v0.w;
        h[4] = (_Float16)v1.x; h[5] = (_Float16)v1.y;
        h[6] = (_Float16)v1.z; h[7] = (_Float16)v1.w;
        const int kbyte = (bkc + u * 8) * 2;
        *reinterpret_cast<f16x8*>(&Bs[brow * 128 + (kbyte ^ ((brow & 7) << 4))]) = h;
      }
    }
    __syncthreads();
#pragma unroll
    for (int kk = 0; kk < 64; kk += 32) {
      const int kbyte = (kk + lq * 8) * 2;
      f16x8 af[4], bf[2];
#pragma unroll
      for (int mt = 0; mt < 4; ++mt) {
        const int row = wm * 64 + mt * 16 + lrow;
        af[mt] = *reinterpret_cast<const f16x8*>(&As[row * 128 + (kbyte ^ ((row & 7) << 4))]);
      }
#pragma unroll
      for (int nt = 0; nt < 2; ++nt) {
        const int row = wn * 32 + nt * 16 + lrow;
        bf[nt] = *reinterpret_cast<const f16x8*>(&Bs[row * 128 + (kbyte ^ ((row & 7) << 4))]);
      }
#pragma unroll
      for (int mt = 0; mt < 4; ++mt)
#pragma unroll
        for (int nt = 0; nt < 2; ++nt)
          acc[mt][nt] = __builtin_amdgcn_mfma_f32_16x16x32_f16(af[mt], bf[nt], acc[mt][nt], 0, 0, 0);
    }
    __syncthreads();
  }

#pragma unroll
  for (int nt = 0; nt < 2; ++nt) {
    const int n = n0 + wn * 32 + nt * 16 + lrow;
    const float bias = b0[n] + b1[n];
#pragma unroll
    for (int mt = 0; mt < 4; ++mt) {
#pragma unroll
      for (int r = 0; r < 4; ++r) {
        const int m = m0 + wm * 64 + mt * 16 + lq * 4 + r;
        C[(size_t)m * N + n] = __float2half_rn(acc[mt][nt][r] + bias);
      }
    }
  }
}

// ---------------------------------------------------------------------------
// LSTM recurrence (v5h — the measured optimum across 11 structural variants:
// 280 us/layer covering both dirs; step floor ~1310 cyc is the serial
// barrier/LDS/dep chain, wave-count-invariant). One 512-thread block per
// (batch, direction) = 128 blocks. Lane (j = tid>>2 unit, kq = tid&3
// k-quarter): 4 gate-rows over quarter-k = 64 dot2/lane. Quad DPP
// allreduce, lane kq activates gate kq (tanh via 2*sigmoid(2x)-1),
// quad_perm broadcasts. h as f16 in LDS, double-buffered. Raw s_barrier
// with lgkmcnt(0)-only wait (xg loads fly across barriers); f16 xg
// prefetch depth 2 via xva/xvb rotation.
// ---------------------------------------------------------------------------
__global__ __launch_bounds__(512, 2) void lstm_seq5h(
    const __half* __restrict__ xg_f, const __half* __restrict__ xg_b,
    const float* __restrict__ Whh_f, const float* __restrict__ Whh_b,
    __half* __restrict__ out) {
  const int b = blockIdx.x;
  const int dir = blockIdx.y;
  const int tid = threadIdx.x;
  const int j = tid >> 2;   // unit 0..127
  const int kq = tid & 3;   // k quarter
  const __half* __restrict__ xg = dir ? xg_b : xg_f;
  const float* __restrict__ Whh = dir ? Whh_b : Whh_f;

  __shared__ unsigned int hbuf[2][64];  // h as f16 pairs, double-buffered

  // Weights: w[g][kk] = f16x2 of row (g*128+j), k = kq*32 + 2*kk, +1
  unsigned int w[4][16];
#pragma unroll
  for (int g = 0; g < 4; ++g) {
    const float4* wr = reinterpret_cast<const float4*>(
        Whh + (size_t)(g * 128 + j) * 128 + kq * 32);
#pragma unroll
    for (int q = 0; q < 8; ++q) {
      float4 v = wr[q];
      __half2 p0 = __floats2half2_rn(v.x, v.y);
      __half2 p1 = __floats2half2_rn(v.z, v.w);
      w[g][2 * q]     = __builtin_bit_cast(unsigned int, p0);
      w[g][2 * q + 1] = __builtin_bit_cast(unsigned int, p1);
    }
  }

  if (tid < 128) hbuf[tid >> 6][tid & 63] = 0u;
  float c = 0.f;
  __syncthreads();

  const int tt0 = dir ? 511 : 0;
  const int stp = dir ? -1 : 1;
  const size_t base = (size_t)b * 512 * 512;
  const int xidx = kq * 128 + j;  // gate kq of unit j

  unsigned short xva = __builtin_bit_cast(unsigned short, xg[base + (size_t)tt0 * 512 + xidx]);
  unsigned short xvb = __builtin_bit_cast(unsigned short, xg[base + (size_t)(tt0 + stp) * 512 + xidx]);

  auto step = [&](int t, unsigned int* rbuf, unsigned int* wbuf, unsigned short& xcur)
      __attribute__((always_inline)) {
    const int tt = tt0 + stp * t;

    // my h quarter: 4 x ds_read_b128, broadcast among 16 lanes each
    const uint4* hc = reinterpret_cast<const uint4*>(&rbuf[kq * 16]);
    uint4 q0 = hc[0], q1 = hc[1], q2 = hc[2], q3 = hc[3];
    unsigned int ha[16];
    ha[0] = q0.x; ha[1] = q0.y; ha[2] = q0.z; ha[3] = q0.w;
    ha[4] = q1.x; ha[5] = q1.y; ha[6] = q1.z; ha[7] = q1.w;
    ha[8] = q2.x; ha[9] = q2.y; ha[10] = q2.z; ha[11] = q2.w;
    ha[12] = q3.x; ha[13] = q3.y; ha[14] = q3.z; ha[15] = q3.w;

    float acc[4] = {0.f, 0.f, 0.f, 0.f};
#pragma unroll
    for (int kk = 0; kk < 16; ++kk) {
#pragma unroll
      for (int g = 0; g < 4; ++g)
        acc[g] = fdot2u(w[g][kk], ha[kk], acc[g]);
    }

    // quad allreduce
#pragma unroll
    for (int g = 0; g < 4; ++g) {
      float a = acc[g];
      a = dpp_add<0xB1>(a);  // xor 1
      a = dpp_add<0x4E>(a);  // xor 2
      acc[g] = a;
    }

    // lane kq activates gate kq
    float a = acc[0];
    a = (kq == 1) ? acc[1] : a;
    a = (kq == 2) ? acc[2] : a;
    a = (kq == 3) ? acc[3] : a;
    a += (float)__builtin_bit_cast(_Float16, xcur);

    // prefetch xg for t+2 (stays in flight across raw barriers)
    {
      const int t2 = t + 2;
      const int tt2 = (t2 < 512) ? (tt0 + stp * t2) : tt0;
      xcur = __builtin_bit_cast(unsigned short, xg[base + (size_t)tt2 * 512 + xidx]);
    }

    const float xs = (kq == 2) ? 2.f * a : a;
    const float y = fast_sigmoid(xs);
    const float act = (kq == 2) ? 2.f * y - 1.f : y;

    const float gi = dpp_mov<0x00>(act);
    const float gf = dpp_mov<0x55>(act);
    const float gg = dpp_mov<0xAA>(act);
    const float go = dpp_mov<0xFF>(act);

    c = gf * c + gi * gg;
    const float h = go * (2.f * fast_sigmoid(2.f * c) - 1.f);

    if (kq == 0) {  // h[j] -> next step's buffer (f16)
      unsigned short us = __builtin_bit_cast(unsigned short, (_Float16)h);
      reinterpret_cast<unsigned short*>(wbuf)[j] = us;
    }
    if (kq == 1) {  // h[j] -> global out (f16)
      out[((size_t)b * 512 + tt) * 256 + dir * 128 + j] = __float2half_rn(h);
    }

    asm volatile("s_waitcnt lgkmcnt(0)" ::: "memory");
    __builtin_amdgcn_s_barrier();
    asm volatile("" ::: "memory");
  };

  for (int it = 0; it < 256; ++it) {
    step(2 * it,     hbuf[0], hbuf[1], xva);
    step(2 * it + 1, hbuf[1], hbuf[0], xvb);
  }
}

// ---------------------------------------------------------------------------
// Launcher
// ---------------------------------------------------------------------------
extern "C" void kernel_launch(void* const* d_in, const int* in_sizes, int n_in,
                              void* d_out, int out_size, void* d_ws, size_t ws_size,
                              hipStream_t stream) {
  (void)in_sizes; (void)n_in; (void)out_size; (void)ws_size;

  const float* x     = (const float*)d_in[0];
  const float* Wih00 = (const float*)d_in[1];
  const float* Whh00 = (const float*)d_in[2];
  const float* bih00 = (const float*)d_in[3];
  const float* bhh00 = (const float*)d_in[4];
  const float* Wih01 = (const float*)d_in[5];
  const float* Whh01 = (const float*)d_in[6];
  const float* bih01 = (const float*)d_in[7];
  const float* bhh01 = (const float*)d_in[8];
  const float* Wih10 = (const float*)d_in[9];
  const float* Whh10 = (const float*)d_in[10];
  const float* bih10 = (const float*)d_in[11];
  const float* bhh10 = (const float*)d_in[12];
  const float* Wih11 = (const float*)d_in[13];
  const float* Whh11 = (const float*)d_in[14];
  const float* bih11 = (const float*)d_in[15];
  const float* bhh11 = (const float*)d_in[16];
  const float* W1 = (const float*)d_in[17];
  const float* b1 = (const float*)d_in[18];
  const float* W2 = (const float*)d_in[19];
  const float* b2 = (const float*)d_in[20];
  float* out = (float*)d_out;

  char* ws = (char*)d_ws;
  __half* xgh_f = (__half*)ws;                          // 32 MB [B,T,512] f16
  __half* xgh_b = (__half*)(ws + ((size_t)32 << 20));   // 32 MB
  __half* bufh  = (__half*)(ws + ((size_t)64 << 20));   // 16 MB [B,T,256] f16
  __half* tmph  = (__half*)(ws + ((size_t)80 << 20));   // 16 MB head intermediate

  const int M = 64 * 512;  // 32768 rows

  // ---- layer 0 ----
  gemm_proj_h<float><<<dim3(M / 128, 8, 2), 256, 0, stream>>>(
      x, Wih00, Wih01, bih00, bhh00, bih01, bhh01, xgh_f, xgh_b, M, 512, 64);
  lstm_seq5h<<<dim3(64, 2), 512, 0, stream>>>(xgh_f, xgh_b, Whh00, Whh01, bufh);

  // ---- layer 1 ----
  gemm_proj_h<__half><<<dim3(M / 128, 8, 2), 256, 0, stream>>>(
      bufh, Wih10, Wih11, bih10, bhh10, bih11, bhh11, xgh_f, xgh_b, M, 512, 256);
  lstm_seq5h<<<dim3(64, 2), 512, 0, stream>>>(xgh_f, xgh_b, Whh10, Whh11, bufh);

  // ---- head ----
  gemm_mfma2<__half, __half, 1><<<dim3(M / 128, 4), 256, 0, stream>>>(
      bufh, W1, b1, nullptr, tmph, M, 256, 256);
  gemm_mfma2<__half, float, 2><<<dim3(M / 128, 1), 256, 0, stream>>>(
      tmph, W2, b2, nullptr, out, M, 64, 256);
}